// Round 6
// baseline (1572.759 us; speedup 1.0000x reference)
//
#include <hip/hip_runtime.h>
#include <math.h>

#define N_ 16
#define C_ 256
#define H_ 128
#define W_ 128
#define TC_ 8
#define S_ 257   // H + W + 1
#define EPS_ 1e-5f
#define NBLK 512
#define PPB 8    // planes per block (NBLK*PPB == N_*C_)

// ws layout (floats):
//   xcat: [N*C][S][2] = 2105344
//   a_h : [N*C][H] (includes a_c) = 524288
//   a_w : [N*C][W] = 524288
//   cnt : grid barrier counter (zeroed per launch via hipMemsetAsync)
#define XCAT_OFF 0
#define AH_OFF   2105344
#define AW_OFF   (AH_OFF + 524288)
#define CNT_OFF  (AW_OFF + 524288)

typedef float f4n __attribute__((ext_vector_type(4)));

__device__ __forceinline__ void gridbar(unsigned* cnt, unsigned target) {
    __syncthreads();
    if (threadIdx.x == 0) {
        __hip_atomic_fetch_add(cnt, 1u, __ATOMIC_ACQ_REL, __HIP_MEMORY_SCOPE_AGENT);
        while (__hip_atomic_load(cnt, __ATOMIC_ACQUIRE, __HIP_MEMORY_SCOPE_AGENT) < target)
            __builtin_amdgcn_s_sleep(8);
    }
    __syncthreads();
}

__global__ __launch_bounds__(256, 2) void mega(
    const float* __restrict__ x,
    const float* __restrict__ w1, const float* __restrict__ b1,
    const float* __restrict__ gam, const float* __restrict__ bet,
    const float* __restrict__ mu, const float* __restrict__ var,
    const float* __restrict__ w2, const float* __restrict__ b2,
    const float* __restrict__ w3, const float* __restrict__ b3,
    const float* __restrict__ w4, const float* __restrict__ b4,
    float* __restrict__ xcat, float* __restrict__ a_h, float* __restrict__ a_w,
    unsigned* __restrict__ cnt, float* __restrict__ out)
{
    const int b = blockIdx.x;
    const int tid = threadIdx.x;
    __shared__ __align__(16) char smraw[37888];

    // ---------------- phase 1: per-plane stats -> xcat (reads x once) -------
    {
        float2 (*rowp)[33] = reinterpret_cast<float2(*)[33]>(smraw);      // 33792 B
        float4* scr_s = reinterpret_cast<float4*>(smraw + 33792);         // 2 KB
        float4* scr_m = reinterpret_cast<float4*>(smraw + 33792 + 2048);  // 2 KB
        const int rg = tid >> 5;

        for (int u = 0; u < PPB; ++u) {
            const int p = b * PPB + u;
            const float4* xt = reinterpret_cast<const float4*>(x) + (size_t)p * 4096;
            float2* xcat2 = reinterpret_cast<float2*>(xcat) + (size_t)p * S_;

            float4 cs = make_float4(0.f, 0.f, 0.f, 0.f);
            float4 cm = make_float4(-INFINITY, -INFINITY, -INFINITY, -INFINITY);

            #pragma unroll
            for (int k = 0; k < 16; ++k) {
                const float4 v = xt[k * 256 + tid];
                cs.x += v.x; cs.y += v.y; cs.z += v.z; cs.w += v.w;
                cm.x = fmaxf(cm.x, v.x); cm.y = fmaxf(cm.y, v.y);
                cm.z = fmaxf(cm.z, v.z); cm.w = fmaxf(cm.w, v.w);
                const float rs = (v.x + v.y) + (v.z + v.w);
                const float rm = fmaxf(fmaxf(v.x, v.y), fmaxf(v.z, v.w));
                rowp[k * 8 + rg][tid & 31] = make_float2(rs, rm);
            }

            cs.x += __shfl_xor(cs.x, 32); cs.y += __shfl_xor(cs.y, 32);
            cs.z += __shfl_xor(cs.z, 32); cs.w += __shfl_xor(cs.w, 32);
            cm.x = fmaxf(cm.x, __shfl_xor(cm.x, 32));
            cm.y = fmaxf(cm.y, __shfl_xor(cm.y, 32));
            cm.z = fmaxf(cm.z, __shfl_xor(cm.z, 32));
            cm.w = fmaxf(cm.w, __shfl_xor(cm.w, 32));

            const int wv = tid >> 6, ln = tid & 63;
            if (ln < 32) { scr_s[wv * 32 + ln] = cs; scr_m[wv * 32 + ln] = cm; }
            __syncthreads();

            if (tid >= 128) {                    // waves 2-3: row stats
                const int h = tid - 128;
                float2 q0 = rowp[h][0];
                float s = q0.x, m = q0.y;
                #pragma unroll
                for (int j = 1; j < 32; ++j) {
                    const float2 q = rowp[h][j];
                    s += q.x; m = fmaxf(m, q.y);
                }
                xcat2[h] = make_float2(s * (1.f / 128.f), m);
            }

            if (tid < 32) {                      // wave 0: cols + global
                const float4 s0 = scr_s[tid],      s1 = scr_s[32 + tid],
                             s2 = scr_s[64 + tid], s3 = scr_s[96 + tid];
                const float4 m0 = scr_m[tid],      m1 = scr_m[32 + tid],
                             m2 = scr_m[64 + tid], m3 = scr_m[96 + tid];
                float4 S, M;
                S.x = (s0.x + s1.x) + (s2.x + s3.x);
                S.y = (s0.y + s1.y) + (s2.y + s3.y);
                S.z = (s0.z + s1.z) + (s2.z + s3.z);
                S.w = (s0.w + s1.w) + (s2.w + s3.w);
                M.x = fmaxf(fmaxf(m0.x, m1.x), fmaxf(m2.x, m3.x));
                M.y = fmaxf(fmaxf(m0.y, m1.y), fmaxf(m2.y, m3.y));
                M.z = fmaxf(fmaxf(m0.z, m1.z), fmaxf(m2.z, m3.z));
                M.w = fmaxf(fmaxf(m0.w, m1.w), fmaxf(m2.w, m3.w));

                const int w0 = 4 * tid;
                xcat2[128 + w0 + 0] = make_float2(S.x * (1.f / 128.f), M.x);
                xcat2[128 + w0 + 1] = make_float2(S.y * (1.f / 128.f), M.y);
                xcat2[128 + w0 + 2] = make_float2(S.z * (1.f / 128.f), M.z);
                xcat2[128 + w0 + 3] = make_float2(S.w * (1.f / 128.f), M.w);

                float gs = (S.x + S.y) + (S.z + S.w);
                float gm = fmaxf(fmaxf(M.x, M.y), fmaxf(M.z, M.w));
                #pragma unroll
                for (int m = 16; m >= 1; m >>= 1) {
                    gs += __shfl_xor(gs, m);
                    gm = fmaxf(gm, __shfl_xor(gm, m));
                }
                if (tid == 0) xcat2[256] = make_float2(gs * (1.f / 16384.f), gm);
            }
            __syncthreads();
        }
    }
    gridbar(cnt, NBLK);

    // ---------------- phase 2: y + a_c/a_h/a_w (blocks 0..15, one per n) ----
    if (b < N_) {
        float* w1s = reinterpret_cast<float*>(smraw);          // 2048
        float* ys  = reinterpret_cast<float*>(smraw) + 2048;   // 4369 (pad 17)
        float* acs = reinterpret_cast<float*>(smraw) + 6432;   // 256
        const int n = b;
        const float2* xc = reinterpret_cast<const float2*>(xcat) + (size_t)n * C_ * S_;

        for (int i = tid; i < TC_ * C_; i += 256) w1s[i] = w1[i];
        __syncthreads();

        float inv[TC_], bas[TC_];
        #pragma unroll
        for (int t = 0; t < TC_; ++t) {
            inv[t] = gam[t] * rsqrtf(var[t] + EPS_);
            bas[t] = bet[t] + (b1[t] - mu[t]) * inv[t];
        }

        // s = tid (0..255)
        {
            const int s = tid;
            float acc[16];
            #pragma unroll
            for (int j = 0; j < 16; ++j) acc[j] = 0.f;
            for (int c = 0; c < C_; ++c) {
                const float2 v = xc[c * S_ + s];
                #pragma unroll
                for (int t = 0; t < TC_; ++t) {
                    const float wv = w1s[t * C_ + c];
                    acc[t * 2 + 0] += v.x * wv;
                    acc[t * 2 + 1] += v.y * wv;
                }
            }
            #pragma unroll
            for (int j = 0; j < 16; ++j) {
                const int t = j >> 1;
                float y = acc[j] * inv[t] + bas[t];
                y = y * fminf(fmaxf(y + 3.f, 0.f), 6.f) * (1.f / 6.f);
                ys[s * 17 + j] = y;
            }
        }
        // s = 256: 32 threads, j = t*2+k
        if (tid < 32) {
            const int j = tid, t = j >> 1, kk = j & 1;
            float z = 0.f;
            for (int c = 0; c < C_; ++c) {
                const float2 v = xc[c * S_ + 256];
                z += (kk ? v.y : v.x) * w1s[t * C_ + c];
            }
            float y = z * inv[t] + bas[t];
            y = y * fminf(fmaxf(y + 3.f, 0.f), 6.f) * (1.f / 6.f);
            ys[256 * 17 + j] = y;
        }
        __syncthreads();

        // a_c (o = tid)
        {
            float z = b4[tid];
            #pragma unroll
            for (int j = 0; j < 16; ++j) z += ys[256 * 17 + j] * w4[tid * 16 + j];
            acs[tid] = 1.f / (1.f + expf(-z));
        }
        __syncthreads();

        // a_h (x a_c), a_w
        const int hw = tid & 127, half = tid >> 7;
        float yh[16], yw[16];
        #pragma unroll
        for (int j = 0; j < 16; ++j) {
            yh[j] = ys[hw * 17 + j];
            yw[j] = ys[(128 + hw) * 17 + j];
        }
        for (int oo = 0; oo < 128; ++oo) {
            const int o = half * 128 + oo;
            float zh = b2[o], zw = b3[o];
            #pragma unroll
            for (int j = 0; j < 16; ++j) {
                zh += yh[j] * w2[o * 16 + j];
                zw += yw[j] * w3[o * 16 + j];
            }
            a_h[((size_t)n * C_ + o) * H_ + hw] = acs[o] / (1.f + expf(-zh));
            a_w[((size_t)n * C_ + o) * W_ + hw] = 1.f / (1.f + expf(-zw));
        }
    }
    gridbar(cnt, 2 * NBLK);

    // ---------------- phase 3: out = x * a_h * a_w (reverse, nt stores) -----
    {
        for (int u = 0; u < PPB; ++u) {
            const int p = (N_ * C_ - 1) - (b * PPB + u);
            const f4n* x4 = reinterpret_cast<const f4n*>(x) + (size_t)p * 4096;
            f4n* o4 = reinterpret_cast<f4n*>(out) + (size_t)p * 4096;
            const float* ah = a_h + (size_t)p * H_;
            const float4* aw4 = reinterpret_cast<const float4*>(a_w) + (size_t)p * 32;

            const float4 a = aw4[tid & 31];      // k-invariant
            #pragma unroll
            for (int k = 0; k < 16; ++k) {
                const int i4 = k * 256 + tid;
                f4n v = x4[i4];
                const float s = ah[i4 >> 5];
                v.x *= s * a.x; v.y *= s * a.y; v.z *= s * a.z; v.w *= s * a.w;
                __builtin_nontemporal_store(v, &o4[i4]);
            }
        }
    }
}

extern "C" void kernel_launch(void* const* d_in, const int* in_sizes, int n_in,
                              void* d_out, int out_size, void* d_ws, size_t ws_size,
                              hipStream_t stream) {
    const float* x   = (const float*)d_in[0];
    const float* w1  = (const float*)d_in[1];
    const float* b1  = (const float*)d_in[2];
    const float* gam = (const float*)d_in[3];
    const float* bet = (const float*)d_in[4];
    const float* mu  = (const float*)d_in[5];
    const float* var = (const float*)d_in[6];
    const float* w2  = (const float*)d_in[7];
    const float* b2  = (const float*)d_in[8];
    const float* w3  = (const float*)d_in[9];
    const float* b3  = (const float*)d_in[10];
    const float* w4  = (const float*)d_in[11];
    const float* b4  = (const float*)d_in[12];

    float* ws   = (float*)d_ws;
    float* xcat = ws + XCAT_OFF;
    float* a_h  = ws + AH_OFF;
    float* a_w  = ws + AW_OFF;
    unsigned* cnt = (unsigned*)(ws + CNT_OFF);
    float* out  = (float*)d_out;

    hipMemsetAsync((void*)cnt, 0, 256, stream);
    mega<<<NBLK, 256, 0, stream>>>(x, w1, b1, gam, bet, mu, var,
                                   w2, b2, w3, b3, w4, b4,
                                   xcat, a_h, a_w, cnt, out);
}

// Round 7
// 190.863 us; speedup vs baseline: 8.2403x; 8.2403x over previous
//
#include <hip/hip_runtime.h>
#include <math.h>

#define N_ 16
#define C_ 256
#define H_ 128
#define W_ 128
#define TC_ 8
#define S_ 257   // H + W + 1
#define EPS_ 1e-5f
#define NBLK 512
#define PPB 8    // planes per block; block b = (n = b>>5, cg = b&31), channels c0 = cg*8 .. +8

// ws layout (floats):
//   xcat: [N*C][S][2] = 2105344
//   cnt : 16 per-n barrier counters, stride 16 uints (64 B)
#define XCAT_OFF 0
#define CNT_OFF  2105344

typedef float f4n __attribute__((ext_vector_type(4)));

__global__ __launch_bounds__(256, 2) void mega(
    const float* __restrict__ x,
    const float* __restrict__ w1, const float* __restrict__ b1,
    const float* __restrict__ gam, const float* __restrict__ bet,
    const float* __restrict__ mu, const float* __restrict__ var,
    const float* __restrict__ w2, const float* __restrict__ b2,
    const float* __restrict__ w3, const float* __restrict__ b3,
    const float* __restrict__ w4, const float* __restrict__ b4,
    float* __restrict__ xcat, unsigned* __restrict__ cnt,
    float* __restrict__ out)
{
    const int b = blockIdx.x;
    const int n = b >> 5, cg = b & 31, c0 = cg * 8;
    const int tid = threadIdx.x;
    __shared__ __align__(16) char smraw[37888];

    // ---------------- phase 1: stats for my 8 planes -> xcat ----------------
    {
        float2 (*rowp)[33] = reinterpret_cast<float2(*)[33]>(smraw);      // 33792 B
        float4* scr_s = reinterpret_cast<float4*>(smraw + 33792);         // 2 KB
        float4* scr_m = reinterpret_cast<float4*>(smraw + 35840);         // 2 KB
        const int rg = tid >> 5;

        for (int u = 0; u < PPB; ++u) {
            const int p = b * PPB + u;
            const float4* xt = reinterpret_cast<const float4*>(x) + (size_t)p * 4096;
            float2* xcat2 = reinterpret_cast<float2*>(xcat) + (size_t)p * S_;

            float4 cs = make_float4(0.f, 0.f, 0.f, 0.f);
            float4 cm = make_float4(-INFINITY, -INFINITY, -INFINITY, -INFINITY);

            #pragma unroll
            for (int k = 0; k < 16; ++k) {
                const float4 v = xt[k * 256 + tid];
                cs.x += v.x; cs.y += v.y; cs.z += v.z; cs.w += v.w;
                cm.x = fmaxf(cm.x, v.x); cm.y = fmaxf(cm.y, v.y);
                cm.z = fmaxf(cm.z, v.z); cm.w = fmaxf(cm.w, v.w);
                const float rs = (v.x + v.y) + (v.z + v.w);
                const float rm = fmaxf(fmaxf(v.x, v.y), fmaxf(v.z, v.w));
                rowp[k * 8 + rg][tid & 31] = make_float2(rs, rm);
            }

            cs.x += __shfl_xor(cs.x, 32); cs.y += __shfl_xor(cs.y, 32);
            cs.z += __shfl_xor(cs.z, 32); cs.w += __shfl_xor(cs.w, 32);
            cm.x = fmaxf(cm.x, __shfl_xor(cm.x, 32));
            cm.y = fmaxf(cm.y, __shfl_xor(cm.y, 32));
            cm.z = fmaxf(cm.z, __shfl_xor(cm.z, 32));
            cm.w = fmaxf(cm.w, __shfl_xor(cm.w, 32));

            const int wv = tid >> 6, ln = tid & 63;
            if (ln < 32) { scr_s[wv * 32 + ln] = cs; scr_m[wv * 32 + ln] = cm; }
            __syncthreads();

            if (tid >= 128) {                    // waves 2-3: row stats
                const int h = tid - 128;
                float2 q0 = rowp[h][0];
                float s = q0.x, m = q0.y;
                #pragma unroll
                for (int j = 1; j < 32; ++j) {
                    const float2 q = rowp[h][j];
                    s += q.x; m = fmaxf(m, q.y);
                }
                xcat2[h] = make_float2(s * (1.f / 128.f), m);
            }

            if (tid < 32) {                      // wave 0: cols + global
                const float4 s0 = scr_s[tid],      s1 = scr_s[32 + tid],
                             s2 = scr_s[64 + tid], s3 = scr_s[96 + tid];
                const float4 m0 = scr_m[tid],      m1 = scr_m[32 + tid],
                             m2 = scr_m[64 + tid], m3 = scr_m[96 + tid];
                float4 S, M;
                S.x = (s0.x + s1.x) + (s2.x + s3.x);
                S.y = (s0.y + s1.y) + (s2.y + s3.y);
                S.z = (s0.z + s1.z) + (s2.z + s3.z);
                S.w = (s0.w + s1.w) + (s2.w + s3.w);
                M.x = fmaxf(fmaxf(m0.x, m1.x), fmaxf(m2.x, m3.x));
                M.y = fmaxf(fmaxf(m0.y, m1.y), fmaxf(m2.y, m3.y));
                M.z = fmaxf(fmaxf(m0.z, m1.z), fmaxf(m2.z, m3.z));
                M.w = fmaxf(fmaxf(m0.w, m1.w), fmaxf(m2.w, m3.w));

                const int w0 = 4 * tid;
                xcat2[128 + w0 + 0] = make_float2(S.x * (1.f / 128.f), M.x);
                xcat2[128 + w0 + 1] = make_float2(S.y * (1.f / 128.f), M.y);
                xcat2[128 + w0 + 2] = make_float2(S.z * (1.f / 128.f), M.z);
                xcat2[128 + w0 + 3] = make_float2(S.w * (1.f / 128.f), M.w);

                float gs = (S.x + S.y) + (S.z + S.w);
                float gm = fmaxf(fmaxf(M.x, M.y), fmaxf(M.z, M.w));
                #pragma unroll
                for (int m = 16; m >= 1; m >>= 1) {
                    gs += __shfl_xor(gs, m);
                    gm = fmaxf(gm, __shfl_xor(gm, m));
                }
                if (tid == 0) xcat2[256] = make_float2(gs * (1.f / 16384.f), gm);
            }
            __syncthreads();
        }
    }

    // ------------- per-n barrier: wait for my 31 siblings -------------------
    // Arrival: one RELEASE add. Spin: RELAXED loads (no cache-invalidate per
    // poll — round 6's acquire-per-poll invalidated L2 continuously and cost
    // ~1.4 ms). One ACQUIRE load after spin exit for visibility.
    __syncthreads();
    if (tid == 0) {
        unsigned* c = cnt + n * 16;
        __hip_atomic_fetch_add(c, 1u, __ATOMIC_RELEASE, __HIP_MEMORY_SCOPE_AGENT);
        while (__hip_atomic_load(c, __ATOMIC_RELAXED, __HIP_MEMORY_SCOPE_AGENT) < 32u)
            __builtin_amdgcn_s_sleep(16);
        (void)__hip_atomic_load(c, __ATOMIC_ACQUIRE, __HIP_MEMORY_SCOPE_AGENT);
    }
    __syncthreads();

    // ---------------- phase 2: y[n] (redundant per block), own a_h/a_w/a_c --
    float* smf = reinterpret_cast<float*>(smraw);
    float* w1s = smf;           // 2048
    float* ys  = smf + 2048;    // 257*17 = 4369 (padded)
    float* acs = smf + 6420;    // 8
    float* ahl = smf + 6432;    // 1024 (16B-aligned: 6432*4 % 16 == 0)
    float* awl = smf + 7456;    // 1024 (16B-aligned)
    {
        const float2* xc = reinterpret_cast<const float2*>(xcat) + (size_t)n * C_ * S_;
        for (int i = tid; i < TC_ * C_; i += 256) w1s[i] = w1[i];
        __syncthreads();

        float inv[TC_], bas[TC_];
        #pragma unroll
        for (int t = 0; t < TC_; ++t) {
            inv[t] = gam[t] * rsqrtf(var[t] + EPS_);
            bas[t] = bet[t] + (b1[t] - mu[t]) * inv[t];
        }

        {   // s = tid
            const int s = tid;
            float acc[16];
            #pragma unroll
            for (int j = 0; j < 16; ++j) acc[j] = 0.f;
            for (int c = 0; c < C_; ++c) {
                const float2 v = xc[c * S_ + s];
                #pragma unroll
                for (int t = 0; t < TC_; ++t) {
                    const float wv = w1s[t * C_ + c];
                    acc[t * 2 + 0] += v.x * wv;
                    acc[t * 2 + 1] += v.y * wv;
                }
            }
            #pragma unroll
            for (int j = 0; j < 16; ++j) {
                const int t = j >> 1;
                float y = acc[j] * inv[t] + bas[t];
                y = y * fminf(fmaxf(y + 3.f, 0.f), 6.f) * (1.f / 6.f);
                ys[s * 17 + j] = y;
            }
        }
        if (tid < 32) {   // s = 256, j = tid
            const int j = tid, t = j >> 1, kk = j & 1;
            float z = 0.f;
            for (int c = 0; c < C_; ++c) {
                const float2 v = xc[c * S_ + 256];
                z += (kk ? v.y : v.x) * w1s[t * C_ + c];
            }
            float y = z * inv[t] + bas[t];
            y = y * fminf(fmaxf(y + 3.f, 0.f), 6.f) * (1.f / 6.f);
            ys[256 * 17 + j] = y;
        }
        __syncthreads();

        if (tid < 8) {    // a_c for my 8 channels
            const int o = c0 + tid;
            float z = b4[o];
            #pragma unroll
            for (int j = 0; j < 16; ++j) z += ys[256 * 17 + j] * w4[o * 16 + j];
            acs[tid] = 1.f / (1.f + expf(-z));
        }
        __syncthreads();

        for (int idx = tid; idx < 8 * 128; idx += 256) {
            const int u = idx >> 7, h = idx & 127, o = c0 + u;
            float zh = b2[o], zw = b3[o];
            #pragma unroll
            for (int j = 0; j < 16; ++j) {
                zh += ys[h * 17 + j]         * w2[o * 16 + j];
                zw += ys[(128 + h) * 17 + j] * w3[o * 16 + j];
            }
            ahl[idx] = acs[u] / (1.f + expf(-zh));   // a_c folded in
            awl[idx] = 1.f / (1.f + expf(-zw));
        }
        __syncthreads();
    }

    // ---------------- phase 3: out = x * a_h * a_w (own planes, nt stores) --
    {
        const float4* awv = reinterpret_cast<const float4*>(awl);
        for (int u = 0; u < PPB; ++u) {
            const int p = b * PPB + u;
            const f4n* x4 = reinterpret_cast<const f4n*>(x) + (size_t)p * 4096;
            f4n* o4 = reinterpret_cast<f4n*>(out) + (size_t)p * 4096;

            const float4 a = awv[u * 32 + (tid & 31)];   // k-invariant
            #pragma unroll
            for (int k = 0; k < 16; ++k) {
                const int i4 = k * 256 + tid;
                f4n v = x4[i4];
                const float s = ahl[u * 128 + k * 8 + (tid >> 5)];
                v.x *= s * a.x; v.y *= s * a.y; v.z *= s * a.z; v.w *= s * a.w;
                __builtin_nontemporal_store(v, &o4[i4]);
            }
        }
    }
}

extern "C" void kernel_launch(void* const* d_in, const int* in_sizes, int n_in,
                              void* d_out, int out_size, void* d_ws, size_t ws_size,
                              hipStream_t stream) {
    const float* x   = (const float*)d_in[0];
    const float* w1  = (const float*)d_in[1];
    const float* b1  = (const float*)d_in[2];
    const float* gam = (const float*)d_in[3];
    const float* bet = (const float*)d_in[4];
    const float* mu  = (const float*)d_in[5];
    const float* var = (const float*)d_in[6];
    const float* w2  = (const float*)d_in[7];
    const float* b2  = (const float*)d_in[8];
    const float* w3  = (const float*)d_in[9];
    const float* b3  = (const float*)d_in[10];
    const float* w4  = (const float*)d_in[11];
    const float* b4  = (const float*)d_in[12];

    float* ws   = (float*)d_ws;
    float* xcat = ws + XCAT_OFF;
    unsigned* cnt = (unsigned*)(ws + CNT_OFF);
    float* out  = (float*)d_out;

    hipMemsetAsync((void*)cnt, 0, 16 * 16 * sizeof(unsigned), stream);
    mega<<<NBLK, 256, 0, stream>>>(x, w1, b1, gam, bet, mu, var,
                                   w2, b2, w3, b3, w4, b4,
                                   xcat, cnt, out);
}